// Round 7
// baseline (107.752 us; speedup 1.0000x reference)
//
#include <hip/hip_runtime.h>
#include <stdint.h>

#define Bd 8
#define Rr 5
#define Nn 1024
#define Dd 512
#define KK (Rr*Dd) /* 2560 */

typedef __attribute__((ext_vector_type(8))) short bf16x8;
typedef __attribute__((ext_vector_type(4))) float f32x4;
typedef unsigned short u16;
typedef unsigned int u32;

__device__ __forceinline__ u16 f2bf(float x){
  union { float f; unsigned u; } v; v.f = x;
  unsigned r = v.u + 0x7FFFu + ((v.u >> 16) & 1u);
  return (u16)(r >> 16);
}

__device__ __forceinline__ void gll16(const void* g, void* l){
  __builtin_amdgcn_global_load_lds(
      (const __attribute__((address_space(1))) void*)g,
      (__attribute__((address_space(3))) void*)l, 16, 0, 0);
}

// ---------------- K1: fused prep ----------------
__global__ __launch_bounds__(256) void k_prep(
    const float* __restrict__ h, const float* __restrict__ W,
    u16* __restrict__ hTp, u16* __restrict__ Wt2, u16* __restrict__ msg){
  __shared__ float t32[32][65];
  const int tid = threadIdx.x;
  const int g = blockIdx.x;
  if (g < 2048){
    const int ut  = g & 31;
    const int dtg = (g >> 5) & 7;
    const int b   = g >> 8;
    const float* hb = h + ((size_t)b*Nn + (size_t)ut*32)*Dd + dtg*64;
    #pragma unroll
    for (int j=0;j<8;j++){
      int e = j*256 + tid;
      int ul = e >> 6, dl = e & 63;
      t32[ul][dl] = hb[(size_t)ul*Dd + dl];
    }
    __syncthreads();
    u16* ob = hTp + (size_t)b*Dd*Nn;
    #pragma unroll
    for (int j=0;j<8;j++){
      int e = j*256 + tid;
      int dtl = e >> 9;
      int rem = e & 511;
      int dr = rem >> 5, uu = rem & 31;
      int dt = dtg*4 + dtl;
      ob[((size_t)ut*32 + dt)*512 + rem] = f2bf(t32[uu][dtl*16 + dr]);
    }
  } else if (g < 3328){
    int idx = (g - 2048)*1024 + tid*4;     // over 512*2560
    int e = idx / KK;
    int k = idx % KK;
    int ri = (k < 2048) ? (1 + (k >> 9)) : 0;
    int d = k & 511;
    f32x4 w = *(const f32x4*)(W + (((size_t)ri*Dd + e)*Dd + d));
    u16 o[4] = { f2bf(w.x), f2bf(w.y), f2bf(w.z), f2bf(w.w) };
    *(uint2*)(Wt2 + idx) = *(uint2*)o;
  } else {
    int q = g - 3328;                      // 0..2047
    int row = q*4 + (tid >> 6);
    int d0 = (tid & 63)*8;
    f32x4 a = *(const f32x4*)(h + (size_t)row*Dd + d0);
    f32x4 c = *(const f32x4*)(h + (size_t)row*Dd + d0 + 4);
    bf16x8 pk;
    pk[0]=(short)f2bf(a.x); pk[1]=(short)f2bf(a.y);
    pk[2]=(short)f2bf(a.z); pk[3]=(short)f2bf(a.w);
    pk[4]=(short)f2bf(c.x); pk[5]=(short)f2bf(c.y);
    pk[6]=(short)f2bf(c.z); pk[7]=(short)f2bf(c.w);
    *(bf16x8*)(msg + (size_t)row*KK + 2048 + d0) = pk;
  }
}

// ---------------- K2: r-fused msg, d-split for 2 blocks/CU ----------------
// msg[b][v][(r-1)*512 + d] = (1/deg) * sum_u adj[b,r,v,u] h[b,u,d]
// Grid 512: bid = dhalf*256 + (b*32 + vt). 256 thr = 4 waves, each 64 d of the
// 256-d half. BM=32 v, BK=64 u, 16 steps. Sibling dhalf-blocks share an XCD
// (adj HBM-read once, L2-shared). Per-step phase order pinned by sched_barrier:
//   PACK adj(t+1) | AISSUE adj(t+2) | MFMA (setprio) | LOADB B(t+1) | barrier
// All waits are vmcnt(8): adj and B never drain (T4).
__global__ __launch_bounds__(256,2) void k_msg(
    const float* __restrict__ adj, const u16* __restrict__ hTp,
    u16* __restrict__ msg){
  __shared__ __align__(16) u16 sA[2][4][32*64];   // 32KB double-buffered adj
  __shared__ float sT[16*260];                    // 16.6KB epilogue transpose
  __shared__ float sDeg[4][32];

  const int tid  = threadIdx.x;
  const int lane = tid & 63;
  const int wave = tid >> 6;          // 0..3
  const int bid = blockIdx.x;
  const int dhalf = bid >> 8;         // 0/1
  const int bv = bid & 255;
  const int b  = bv >> 5;
  const int vt = bv & 31;
  const int v0 = vt * 32;
  const float* adjb = adj + (((size_t)b*Rr + 1)*Nn + v0)*Nn;  // r=1 base
  const u16* hTpb = hTp + (size_t)b*Dd*Nn;

  const int srow = tid >> 3;          // 0..31
  const int sc   = tid & 7;           // 8-f32 chunk
  const size_t aoff = (size_t)srow*Nn + sc*8;
  const int wslot = sc ^ (srow & 7);  // swizzled 16B slot in 128B row

  float deg[4] = {0.f,0.f,0.f,0.f};
  f32x4 ar0[4], ar1[4];               // 8-f32 per relation, in-flight
  f32x4 acc[4][2][4];
  #pragma unroll
  for (int ri=0;ri<4;ri++)
    #pragma unroll
    for (int m=0;m<2;m++)
      #pragma unroll
      for (int n=0;n<4;n++) acc[ri][m][n] = (f32x4){0.f,0.f,0.f,0.f};

  const int rlo = lane & 15, ch = lane >> 4;
  const int boff = rlo*32 + ch*8;

  #define AISSUE(T) do {                                                      \
    _Pragma("unroll")                                                         \
    for (int ri=0;ri<4;ri++){                                                 \
      const float* ap = adjb + (size_t)ri*Nn*Nn + (size_t)(T)*64 + aoff;      \
      ar0[ri] = *(const f32x4*)ap;                                            \
      ar1[ri] = *(const f32x4*)(ap + 4);                                      \
    }                                                                         \
  } while(0)

  #define PACK(BUFI) do {                                                     \
    _Pragma("unroll")                                                         \
    for (int ri=0;ri<4;ri++){                                                 \
      f32x4 p0 = ar0[ri], p1 = ar1[ri];                                       \
      deg[ri] += p0.x+p0.y+p0.z+p0.w + p1.x+p1.y+p1.z+p1.w;                   \
      uint4 pk;  /* adj in {0,1}: truncation exact */                         \
      pk.x = (__float_as_uint(p0.x)>>16) | (__float_as_uint(p0.y) & 0xFFFF0000u);\
      pk.y = (__float_as_uint(p0.z)>>16) | (__float_as_uint(p0.w) & 0xFFFF0000u);\
      pk.z = (__float_as_uint(p1.x)>>16) | (__float_as_uint(p1.y) & 0xFFFF0000u);\
      pk.w = (__float_as_uint(p1.z)>>16) | (__float_as_uint(p1.w) & 0xFFFF0000u);\
      *(uint4*)((char*)sA[BUFI][ri] + srow*128 + (wslot<<4)) = pk;            \
    }                                                                         \
  } while(0)

  #define LOADB(T) do {                                                       \
    _Pragma("unroll")                                                         \
    for (int kk=0;kk<2;kk++){                                                 \
      _Pragma("unroll")                                                       \
      for (int n=0;n<4;n++){                                                  \
        const int dt = dhalf*16 + (wave<<2) + n;                              \
        bfr[kk][n] = *(const bf16x8*)(hTpb +                                  \
            (((size_t)((T)*2+kk)*32 + dt)<<9) + boff);                        \
      }                                                                       \
    }                                                                         \
  } while(0)

  #define MSTEP(BUFI) do {                                                    \
    const char* abase = (const char*)sA[BUFI];                                \
    __builtin_amdgcn_s_setprio(1);                                            \
    _Pragma("unroll")                                                         \
    for (int kk=0;kk<2;kk++){                                                 \
      _Pragma("unroll")                                                       \
      for (int ri=0;ri<4;ri++){                                               \
        bf16x8 af[2];                                                         \
        _Pragma("unroll")                                                     \
        for (int m=0;m<2;m++){                                                \
          const int row = m*16 + rlo;                                         \
          const int g = kk*4 + ch;                                            \
          af[m] = *(const bf16x8*)(abase + ri*4096 + row*128                  \
                    + ((g ^ (row&7))<<4));                                    \
        }                                                                     \
        _Pragma("unroll")                                                     \
        for (int m=0;m<2;m++)                                                 \
          _Pragma("unroll")                                                   \
          for (int n=0;n<4;n++)                                               \
            acc[ri][m][n] = __builtin_amdgcn_mfma_f32_16x16x32_bf16(          \
                af[m], bfr[kk][n], acc[ri][m][n], 0, 0, 0);                   \
      }                                                                       \
    }                                                                         \
    __builtin_amdgcn_s_setprio(0);                                            \
  } while(0)

  #define FENCE() __builtin_amdgcn_sched_barrier(0)
  #define STEP_BARRIER() do {                                                 \
    asm volatile("s_waitcnt lgkmcnt(0)" ::: "memory");                        \
    FENCE();                                                                  \
    __builtin_amdgcn_s_barrier();                                             \
    FENCE();                                                                  \
  } while(0)

  bf16x8 bfr[2][4];

  // prologue
  AISSUE(0);
  PACK(0);
  __syncthreads();
  AISSUE(1);
  FENCE();
  LOADB(0);
  FENCE();

  for (int t = 0; t < 15; ++t){
    PACK((t+1)&1);            // consumes adj(t+1), waits vmcnt<=8 (B newer)
    FENCE();
    if (t < 14) AISSUE(t+2);  // adj(t+2) in flight across >=1 full step
    FENCE();
    MSTEP(t&1);               // waits vmcnt<=8 (adj outstanding)
    FENCE();
    LOADB(t+1);               // B(t+1) crosses the barrier in registers
    STEP_BARRIER();
  }
  MSTEP(1);                   // t=15
  #undef AISSUE
  #undef PACK
  #undef LOADB
  #undef MSTEP
  #undef FENCE
  #undef STEP_BARRIER

  // deg reduce over the 8 threads sharing srow (lane bits 0..2)
  #pragma unroll
  for (int ri=0;ri<4;ri++){
    float d = deg[ri];
    d += __shfl_xor(d, 1); d += __shfl_xor(d, 2); d += __shfl_xor(d, 4);
    if (sc == 0) sDeg[ri][srow] = d;
  }
  __syncthreads();

  // Epilogue: per (ri, half): scale -> sT[16][260] -> dense row stores
  u16* mb = msg + ((size_t)b*Nn + v0)*KK;
  #pragma unroll
  for (int ri=0;ri<4;ri++){
    #pragma unroll
    for (int hh=0;hh<2;hh++){
      #pragma unroll
      for (int reg=0;reg<4;reg++){
        const int rl = ch*4 + reg;
        const float inv = 1.0f / fmaxf(sDeg[ri][hh*16 + rl], 1.0f);
        #pragma unroll
        for (int n=0;n<4;n++){
          const int col = (wave<<6) + n*16 + rlo;   // 0..255
          sT[rl*260 + col] = acc[ri][hh][n][reg] * inv;
        }
      }
      __syncthreads();
      {
        const int row = tid >> 4;        // 0..15
        const int base = tid & 15;
        u16* orow = mb + (size_t)(hh*16 + row)*KK + ri*512 + dhalf*256;
        #pragma unroll
        for (int j=0;j<8;j++){
          const int unit = base + 16*j;  // 8B unit, 0..127
          float lo = sT[row*260 + 2*unit];
          float hi = sT[row*260 + 2*unit + 1];
          u32 pk = (u32)f2bf(lo) | ((u32)f2bf(hi) << 16);
          *(u32*)(orow + 2*unit) = pk;
        }
      }
      __syncthreads();
    }
  }
}

// ---------------- K3: agg[b][v][e] = sum_k msg[b][v][k] * Wt2[e][k], K=2560
__global__ __launch_bounds__(512,4) void k_agg(
    const u16* __restrict__ msg, const u16* __restrict__ Wt,
    float* __restrict__ agg){
  __shared__ __align__(16) u16 sA[2][64*64];
  __shared__ __align__(16) u16 sB[2][128*64];
  const int tid = threadIdx.x;
  const int lane = tid & 63, wave = tid >> 6;
  const int wm = wave >> 2, wn = wave & 3;
  const int g = blockIdx.x;
  const int et = g >> 7;
  const int bv = g & 127;
  const int b  = bv >> 4;
  const int vt = bv & 15;
  const int v0 = vt*64, e0 = et*128;
  const u16* Ab = msg + ((size_t)b*Nn + v0)*KK;
  const u16* Bb = Wt + (size_t)e0*KK;

  f32x4 acc[2][2];
  #pragma unroll
  for (int m=0;m<2;m++)
    #pragma unroll
    for (int n=0;n<2;n++) acc[m][n] = (f32x4){0.f,0.f,0.f,0.f};

  #define STAGE(buf, kt) do {                                              \
    { int c = tid; int row_ = c>>3, chg = (c&7) ^ (row_&7);                \
      gll16(Ab + (size_t)row_*KK + (kt)*64 + chg*8,                        \
            (char*)sA[buf] + ((size_t)(wave<<6))*16); }                    \
    _Pragma("unroll")                                                      \
    for (int i=0;i<2;i++){                                                 \
      int c = i*512 + tid; int row_ = c>>3, chg = (c&7) ^ (row_&7);        \
      gll16(Bb + (size_t)row_*KK + (kt)*64 + chg*8,                        \
            (char*)sB[buf] + ((size_t)(i*512 + (wave<<6)))*16);            \
    }                                                                      \
  } while(0)

  STAGE(0, 0);
  __syncthreads();

  const int ch = lane >> 4, rlo = lane & 15;

  for (int kt = 0; kt < KK/64; ++kt){
    if (kt < KK/64 - 1) STAGE((kt+1)&1, kt+1);
    const char* a  = (const char*)sA[kt&1];
    const char* bb = (const char*)sB[kt&1];
    #pragma unroll
    for (int kk=0; kk<2; ++kk){
      bf16x8 af[2], bfx[2];
      #pragma unroll
      for (int m=0;m<2;m++){
        const int row = wm*32 + m*16 + rlo;
        af[m] = *(const bf16x8*)(a + row*128 + ((((kk<<2)+ch) ^ (row&7))<<4));
      }
      #pragma unroll
      for (int n=0;n<2;n++){
        const int row = wn*32 + n*16 + rlo;
        bfx[n] = *(const bf16x8*)(bb + row*128 + ((((kk<<2)+ch) ^ (row&7))<<4));
      }
      #pragma unroll
      for (int m=0;m<2;m++)
        #pragma unroll
        for (int n=0;n<2;n++)
          acc[m][n] = __builtin_amdgcn_mfma_f32_16x16x32_bf16(af[m], bfx[n], acc[m][n], 0, 0, 0);
    }
    __syncthreads();
  }
  #undef STAGE

  float* ob = agg + ((size_t)b*Nn + v0)*Dd + e0;
  #pragma unroll
  for (int m=0;m<2;m++)
    #pragma unroll
    for (int reg=0;reg<4;reg++){
      const int row = wm*32 + m*16 + ((lane>>4)<<2) + reg;
      #pragma unroll
      for (int n=0;n<2;n++){
        const int col = wn*32 + n*16 + (lane & 15);
        ob[(size_t)row*Dd + col] = acc[m][n][reg];
      }
    }
}

// ---------------- K4: out = LN(relu(agg) + h) * gamma + beta; 4 rows/block
__global__ __launch_bounds__(256,4) void k_ln(
    const float* __restrict__ agg, const float* __restrict__ h,
    const float* __restrict__ gamma, const float* __restrict__ beta,
    float* __restrict__ out){
  const int row = blockIdx.x*4 + (threadIdx.x >> 6);
  const int lane = threadIdx.x & 63;
  const float* a  = agg + (size_t)row*Dd;
  const float* hh = h   + (size_t)row*Dd;
  float x[8];
  float sum = 0.f, sq = 0.f;
  #pragma unroll
  for (int q=0;q<2;q++){
    f32x4 av = *(const f32x4*)(a  + ((size_t)q*64+lane)*4);
    f32x4 hv = *(const f32x4*)(hh + ((size_t)q*64+lane)*4);
    #pragma unroll
    for (int k=0;k<4;k++){
      float v = fmaxf(av[k], 0.f) + hv[k];
      x[q*4+k] = v; sum += v; sq += v*v;
    }
  }
  #pragma unroll
  for (int off=32; off; off>>=1){
    sum += __shfl_xor(sum, off);
    sq  += __shfl_xor(sq,  off);
  }
  const float mu  = sum * (1.f/(float)Dd);
  const float var = sq * (1.f/(float)Dd) - mu*mu;
  const float rstd = rsqrtf(var + 1e-5f);
  float* o = out + (size_t)row*Dd;
  #pragma unroll
  for (int q=0;q<2;q++){
    f32x4 g  = *(const f32x4*)(gamma + ((size_t)q*64+lane)*4);
    f32x4 be = *(const f32x4*)(beta  + ((size_t)q*64+lane)*4);
    f32x4 ov;
    #pragma unroll
    for (int k=0;k<4;k++)
      ov[k] = (x[q*4+k] - mu) * rstd * g[k] + be[k];
    *(f32x4*)(o + ((size_t)q*64+lane)*4) = ov;
  }
}

extern "C" void kernel_launch(void* const* d_in, const int* in_sizes, int n_in,
                              void* d_out, int out_size, void* d_ws, size_t ws_size,
                              hipStream_t stream){
  const float* h     = (const float*)d_in[0];
  const float* adj   = (const float*)d_in[1];
  const float* W     = (const float*)d_in[2];
  const float* gamma = (const float*)d_in[3];
  const float* beta  = (const float*)d_in[4];
  float* out = (float*)d_out;
  char* ws = (char*)d_ws;

  u16*  hTp = (u16*)(ws);                 //  8,388,608  (Bd*Dd*Nn*2)
  u16*  Wt2 = (u16*)(ws + 8388608);       //  2,621,440  (Dd*KK*2)
  u16*  msg = (u16*)(ws + 11010048);      // 41,943,040  (Bd*Nn*KK*2)
  float* agg = (float*)(ws + 52953088);   // 16,777,216  (Bd*Nn*Dd*4)

  k_prep<<<dim3(5376), dim3(256), 0, stream>>>(h, W, hTp, Wt2, msg);
  k_msg <<<dim3(512), dim3(256), 0, stream>>>(adj, hTp, msg);
  k_agg <<<dim3(Bd*(Nn/64)*(Dd/128)), dim3(512), 0, stream>>>(msg, Wt2, agg);
  k_ln  <<<dim3(Bd*Nn/4), dim3(256), 0, stream>>>(agg, h, gamma, beta, out);
}

// Round 8
// 96.025 us; speedup vs baseline: 1.1221x; 1.1221x over previous
//
#include <hip/hip_runtime.h>
#include <stdint.h>

#define Bd 8
#define Rr 5
#define Nn 1024
#define Dd 512
#define KK (Rr*Dd) /* 2560 */

typedef __attribute__((ext_vector_type(8))) short bf16x8;
typedef __attribute__((ext_vector_type(4))) float f32x4;
typedef unsigned short u16;
typedef unsigned int u32;

__device__ __forceinline__ u16 f2bf(float x){
  union { float f; unsigned u; } v; v.f = x;
  unsigned r = v.u + 0x7FFFu + ((v.u >> 16) & 1u);
  return (u16)(r >> 16);
}

__device__ __forceinline__ void gll16(const void* g, void* l){
  __builtin_amdgcn_global_load_lds(
      (const __attribute__((address_space(1))) void*)g,
      (__attribute__((address_space(3))) void*)l, 16, 0, 0);
}

// ---------------- K1: fused prep ----------------
__global__ __launch_bounds__(256) void k_prep(
    const float* __restrict__ h, const float* __restrict__ W,
    u16* __restrict__ hTp, u16* __restrict__ Wt2, u16* __restrict__ msg){
  __shared__ float t32[32][65];
  const int tid = threadIdx.x;
  const int g = blockIdx.x;
  if (g < 2048){
    const int ut  = g & 31;
    const int dtg = (g >> 5) & 7;
    const int b   = g >> 8;
    const float* hb = h + ((size_t)b*Nn + (size_t)ut*32)*Dd + dtg*64;
    #pragma unroll
    for (int j=0;j<8;j++){
      int e = j*256 + tid;
      int ul = e >> 6, dl = e & 63;
      t32[ul][dl] = hb[(size_t)ul*Dd + dl];
    }
    __syncthreads();
    u16* ob = hTp + (size_t)b*Dd*Nn;
    #pragma unroll
    for (int j=0;j<8;j++){
      int e = j*256 + tid;
      int dtl = e >> 9;
      int rem = e & 511;
      int dr = rem >> 5, uu = rem & 31;
      int dt = dtg*4 + dtl;
      ob[((size_t)ut*32 + dt)*512 + rem] = f2bf(t32[uu][dtl*16 + dr]);
    }
  } else if (g < 3328){
    int idx = (g - 2048)*1024 + tid*4;     // over 512*2560
    int e = idx / KK;
    int k = idx % KK;
    int ri = (k < 2048) ? (1 + (k >> 9)) : 0;
    int d = k & 511;
    f32x4 w = *(const f32x4*)(W + (((size_t)ri*Dd + e)*Dd + d));
    u16 o[4] = { f2bf(w.x), f2bf(w.y), f2bf(w.z), f2bf(w.w) };
    *(uint2*)(Wt2 + idx) = *(uint2*)o;
  } else {
    int q = g - 3328;                      // 0..2047
    int row = q*4 + (tid >> 6);
    int d0 = (tid & 63)*8;
    f32x4 a = *(const f32x4*)(h + (size_t)row*Dd + d0);
    f32x4 c = *(const f32x4*)(h + (size_t)row*Dd + d0 + 4);
    bf16x8 pk;
    pk[0]=(short)f2bf(a.x); pk[1]=(short)f2bf(a.y);
    pk[2]=(short)f2bf(a.z); pk[3]=(short)f2bf(a.w);
    pk[4]=(short)f2bf(c.x); pk[5]=(short)f2bf(c.y);
    pk[6]=(short)f2bf(c.z); pk[7]=(short)f2bf(c.w);
    *(bf16x8*)(msg + (size_t)row*KK + 2048 + d0) = pk;
  }
}

// ---------------- K2: r-fused msg, relations 1..4, channel-staggered ----------
// msg[b][v][(r-1)*512+d] = (1/deg) * sum_u adj[b,r,v,u] h[b,u,d]
// BM=32, BN=512, BK=64, 16 steps, grid 256 (1 block/CU), 512 thr = 8 waves.
// Per-block staggered u-tile order tt=(t+bid)&15: breaks the lockstep
// column-window march (adj row stride = 4KB pow2) that camps on a subset of
// HBM channels. Raw s_barrier + lgkmcnt(0)-only (vmcnt never drained).
__global__ __launch_bounds__(512,2) void k_msg(
    const float* __restrict__ adj, const u16* __restrict__ hTp,
    u16* __restrict__ msg){
  __shared__ __align__(16) u16 sA[2][4][32*64];   // 32KB double-buffered adj
  __shared__ float sT[16*516];                    // 33KB epilogue transpose
  __shared__ float sDeg[4][32];

  const int tid  = threadIdx.x;
  const int lane = tid & 63;
  const int wave = tid >> 6;
  const int b  = blockIdx.x & 7;     // b -> XCD (L2 locality for hTp[b])
  const int vt = blockIdx.x >> 3;
  const int v0 = vt * 32;
  const int t0 = blockIdx.x & 15;    // channel stagger
  const float* adjb = adj + (((size_t)b*Rr + 1)*Nn + v0)*Nn;  // r=1 base
  const u16* hTpb = hTp + (size_t)b*Dd*Nn;

  const int srow = tid >> 4;         // 0..31
  const int sc   = tid & 15;         // 16B chunk
  const size_t aoff = (size_t)srow*Nn + sc*4;
  const int wslot = sc ^ ((srow & 7) << 1);

  float deg[4] = {0.f,0.f,0.f,0.f};
  f32x4 aregA[4], aregB[4];
  f32x4 acc[4][2][4];
  #pragma unroll
  for (int ri=0;ri<4;ri++)
    #pragma unroll
    for (int m=0;m<2;m++)
      #pragma unroll
      for (int n=0;n<4;n++) acc[ri][m][n] = (f32x4){0.f,0.f,0.f,0.f};

  const int rlo = lane & 15, ch = lane >> 4;
  const int boff = rlo*32 + ch*8;

  #define TT(x) (((x) + t0) & 15)

  #define AISSUE(DST, T) do {                                                 \
    _Pragma("unroll")                                                         \
    for (int ri=0;ri<4;ri++)                                                  \
      DST[ri] = *(const f32x4*)(adjb + (size_t)ri*Nn*Nn + (size_t)(T)*64 + aoff); \
  } while(0)

  #define PACK(SRC, BUFI) do {                                                \
    _Pragma("unroll")                                                         \
    for (int ri=0;ri<4;ri++){                                                 \
      f32x4 p = SRC[ri];                                                      \
      deg[ri] += p.x+p.y+p.z+p.w;                                             \
      uint2 pk;  /* adj in {0,1}: truncation exact */                         \
      pk.x = (__float_as_uint(p.x)>>16) | (__float_as_uint(p.y) & 0xFFFF0000u);\
      pk.y = (__float_as_uint(p.z)>>16) | (__float_as_uint(p.w) & 0xFFFF0000u);\
      *(uint2*)((char*)sA[BUFI][ri] + srow*128 + wslot*8) = pk;               \
    }                                                                         \
  } while(0)

  #define LOADB(DST, T) do {                                                  \
    _Pragma("unroll")                                                         \
    for (int kk=0;kk<2;kk++){                                                 \
      const u16* bp = hTpb + ((((size_t)((T)*2+kk))*32 + (wave<<2))<<9) + boff;\
      _Pragma("unroll")                                                       \
      for (int n=0;n<4;n++)                                                   \
        DST[kk][n] = *(const bf16x8*)(bp + ((size_t)n<<9));                   \
    }                                                                         \
  } while(0)

  #define MSTEP(BFR, BUFI) do {                                               \
    const char* abase = (const char*)sA[BUFI];                                \
    _Pragma("unroll")                                                         \
    for (int kk=0;kk<2;kk++){                                                 \
      _Pragma("unroll")                                                       \
      for (int ri=0;ri<4;ri++){                                               \
        bf16x8 af[2];                                                         \
        _Pragma("unroll")                                                     \
        for (int m=0;m<2;m++){                                                \
          const int row = m*16 + rlo;                                         \
          af[m] = *(const bf16x8*)(abase + ri*4096 + row*128                  \
                    + (((kk*8 + ch*2) ^ ((row&7)<<1))<<3));                   \
        }                                                                     \
        _Pragma("unroll")                                                     \
        for (int m=0;m<2;m++)                                                 \
          _Pragma("unroll")                                                   \
          for (int n=0;n<4;n++)                                               \
            acc[ri][m][n] = __builtin_amdgcn_mfma_f32_16x16x32_bf16(          \
                af[m], BFR[kk][n], acc[ri][m][n], 0, 0, 0);                   \
      }                                                                       \
    }                                                                         \
  } while(0)

  #define STEP_BARRIER() do {                                                 \
    asm volatile("s_waitcnt lgkmcnt(0)" ::: "memory");                        \
    __builtin_amdgcn_sched_barrier(0);                                        \
    __builtin_amdgcn_s_barrier();                                             \
    __builtin_amdgcn_sched_barrier(0);                                        \
  } while(0)

  // prologue: tile TT(0) -> buf0, then issue adj(TT(1))
  AISSUE(aregA, TT(0));
  PACK(aregA, 0);
  __syncthreads();
  AISSUE(aregA, TT(1));

  for (int t = 0; t < 14; t += 2){
    { // even body t: buf0 holds adj(TT(t)); aregA = adj(TT(t+1)) in flight
      bf16x8 bfr[2][4];
      LOADB(bfr, TT(t));
      AISSUE(aregB, TT(t+2));
      PACK(aregA, 1);          // adj(TT(t+1)) -> buf1
      MSTEP(bfr, 0);
      STEP_BARRIER();
    }
    { // odd body t+1
      bf16x8 bfr[2][4];
      LOADB(bfr, TT(t+1));
      AISSUE(aregA, TT(t+3));  // max t=12 -> TT(15)
      PACK(aregB, 0);          // adj(TT(t+2)) -> buf0
      MSTEP(bfr, 1);
      STEP_BARRIER();
    }
  }
  { // t = 14: aregA = adj(TT(15))
    bf16x8 bfr[2][4];
    LOADB(bfr, TT(14));
    PACK(aregA, 1);
    MSTEP(bfr, 0);
    STEP_BARRIER();
  }
  { // t = 15
    bf16x8 bfr[2][4];
    LOADB(bfr, TT(15));
    MSTEP(bfr, 1);
  }
  #undef TT
  #undef AISSUE
  #undef PACK
  #undef LOADB
  #undef MSTEP
  #undef STEP_BARRIER

  // deg reduce over the 16 threads sharing srow
  #pragma unroll
  for (int ri=0;ri<4;ri++){
    float d = deg[ri];
    d += __shfl_xor(d, 1); d += __shfl_xor(d, 2);
    d += __shfl_xor(d, 4); d += __shfl_xor(d, 8);
    if (sc == 0) sDeg[ri][srow] = d;
  }
  __syncthreads();

  // Epilogue: per (ri, half): scale -> swizzled sT -> dense 1KB-row stores
  u16* mb = msg + ((size_t)b*Nn + v0)*KK;
  #pragma unroll
  for (int ri=0;ri<4;ri++){
    #pragma unroll
    for (int hh=0;hh<2;hh++){
      #pragma unroll
      for (int reg=0;reg<4;reg++){
        const int rl = ch*4 + reg;
        const float inv = 1.0f / fmaxf(sDeg[ri][hh*16 + rl], 1.0f);
        #pragma unroll
        for (int n=0;n<4;n++){
          const int col = (wave<<6) + n*16 + rlo;
          const int colw = col ^ (((col>>5)&7)<<2);
          sT[rl*516 + colw] = acc[ri][hh][n][reg] * inv;
        }
      }
      __syncthreads();
      #pragma unroll
      for (int s=0;s<2;s++){
        const int rl = wave*2 + s;
        const int m5 = lane >> 2;
        const int e  = m5 & 7;
        const int j0 = (2*lane) & 7;
        f32x4 lo = *(const f32x4*)&sT[rl*516 + (m5<<5) + (((j0  ) ^ e)<<2)];
        f32x4 hi = *(const f32x4*)&sT[rl*516 + (m5<<5) + (((j0+1) ^ e)<<2)];
        bf16x8 pk;
        pk[0]=(short)f2bf(lo.x); pk[1]=(short)f2bf(lo.y);
        pk[2]=(short)f2bf(lo.z); pk[3]=(short)f2bf(lo.w);
        pk[4]=(short)f2bf(hi.x); pk[5]=(short)f2bf(hi.y);
        pk[6]=(short)f2bf(hi.z); pk[7]=(short)f2bf(hi.w);
        *(bf16x8*)(mb + (size_t)(hh*16 + rl)*KK + ri*512 + lane*8) = pk;
      }
      __syncthreads();
    }
  }
}

// ---------------- K3: agg[b][v][e] = sum_k msg[b][v][k] * Wt2[e][k], K=2560
__global__ __launch_bounds__(512,4) void k_agg(
    const u16* __restrict__ msg, const u16* __restrict__ Wt,
    float* __restrict__ agg){
  __shared__ __align__(16) u16 sA[2][64*64];
  __shared__ __align__(16) u16 sB[2][128*64];
  const int tid = threadIdx.x;
  const int lane = tid & 63, wave = tid >> 6;
  const int wm = wave >> 2, wn = wave & 3;
  const int g = blockIdx.x;
  const int et = g >> 7;
  const int bv = g & 127;
  const int b  = bv >> 4;
  const int vt = bv & 15;
  const int v0 = vt*64, e0 = et*128;
  const u16* Ab = msg + ((size_t)b*Nn + v0)*KK;
  const u16* Bb = Wt + (size_t)e0*KK;

  f32x4 acc[2][2];
  #pragma unroll
  for (int m=0;m<2;m++)
    #pragma unroll
    for (int n=0;n<2;n++) acc[m][n] = (f32x4){0.f,0.f,0.f,0.f};

  #define STAGE(buf, kt) do {                                              \
    { int c = tid; int row_ = c>>3, chg = (c&7) ^ (row_&7);                \
      gll16(Ab + (size_t)row_*KK + (kt)*64 + chg*8,                        \
            (char*)sA[buf] + ((size_t)(wave<<6))*16); }                    \
    _Pragma("unroll")                                                      \
    for (int i=0;i<2;i++){                                                 \
      int c = i*512 + tid; int row_ = c>>3, chg = (c&7) ^ (row_&7);        \
      gll16(Bb + (size_t)row_*KK + (kt)*64 + chg*8,                        \
            (char*)sB[buf] + ((size_t)(i*512 + (wave<<6)))*16);            \
    }                                                                      \
  } while(0)

  STAGE(0, 0);
  __syncthreads();

  const int ch = lane >> 4, rlo = lane & 15;

  for (int kt = 0; kt < KK/64; ++kt){
    if (kt < KK/64 - 1) STAGE((kt+1)&1, kt+1);
    const char* a  = (const char*)sA[kt&1];
    const char* bb = (const char*)sB[kt&1];
    #pragma unroll
    for (int kk=0; kk<2; ++kk){
      bf16x8 af[2], bfx[2];
      #pragma unroll
      for (int m=0;m<2;m++){
        const int row = wm*32 + m*16 + rlo;
        af[m] = *(const bf16x8*)(a + row*128 + ((((kk<<2)+ch) ^ (row&7))<<4));
      }
      #pragma unroll
      for (int n=0;n<2;n++){
        const int row = wn*32 + n*16 + rlo;
        bfx[n] = *(const bf16x8*)(bb + row*128 + ((((kk<<2)+ch) ^ (row&7))<<4));
      }
      #pragma unroll
      for (int m=0;m<2;m++)
        #pragma unroll
        for (int n=0;n<2;n++)
          acc[m][n] = __builtin_amdgcn_mfma_f32_16x16x32_bf16(af[m], bfx[n], acc[m][n], 0, 0, 0);
    }
    __syncthreads();
  }
  #undef STAGE

  float* ob = agg + ((size_t)b*Nn + v0)*Dd + e0;
  #pragma unroll
  for (int m=0;m<2;m++)
    #pragma unroll
    for (int reg=0;reg<4;reg++){
      const int row = wm*32 + m*16 + ((lane>>4)<<2) + reg;
      #pragma unroll
      for (int n=0;n<2;n++){
        const int col = wn*32 + n*16 + (lane & 15);
        ob[(size_t)row*Dd + col] = acc[m][n][reg];
      }
    }
}

// ---------------- K4: out = LN(relu(agg) + h) * gamma + beta; 4 rows/block
__global__ __launch_bounds__(256,4) void k_ln(
    const float* __restrict__ agg, const float* __restrict__ h,
    const float* __restrict__ gamma, const float* __restrict__ beta,
    float* __restrict__ out){
  const int row = blockIdx.x*4 + (threadIdx.x >> 6);
  const int lane = threadIdx.x & 63;
  const float* a  = agg + (size_t)row*Dd;
  const float* hh = h   + (size_t)row*Dd;
  float x[8];
  float sum = 0.f, sq = 0.f;
  #pragma unroll
  for (int q=0;q<2;q++){
    f32x4 av = *(const f32x4*)(a  + ((size_t)q*64+lane)*4);
    f32x4 hv = *(const f32x4*)(hh + ((size_t)q*64+lane)*4);
    #pragma unroll
    for (int k=0;k<4;k++){
      float v = fmaxf(av[k], 0.f) + hv[k];
      x[q*4+k] = v; sum += v; sq += v*v;
    }
  }
  #pragma unroll
  for (int off=32; off; off>>=1){
    sum += __shfl_xor(sum, off);
    sq  += __shfl_xor(sq,  off);
  }
  const float mu  = sum * (1.f/(float)Dd);
  const float var = sq * (1.f/(float)Dd) - mu*mu;
  const float rstd = rsqrtf(var + 1e-5f);
  float* o = out + (size_t)row*Dd;
  #pragma unroll
  for (int q=0;q<2;q++){
    f32x4 g  = *(const f32x4*)(gamma + ((size_t)q*64+lane)*4);
    f32x4 be = *(const f32x4*)(beta  + ((size_t)q*64+lane)*4);
    f32x4 ov;
    #pragma unroll
    for (int k=0;k<4;k++)
      ov[k] = (x[q*4+k] - mu) * rstd * g[k] + be[k];
    *(f32x4*)(o + ((size_t)q*64+lane)*4) = ov;
  }
}

extern "C" void kernel_launch(void* const* d_in, const int* in_sizes, int n_in,
                              void* d_out, int out_size, void* d_ws, size_t ws_size,
                              hipStream_t stream){
  const float* h     = (const float*)d_in[0];
  const float* adj   = (const float*)d_in[1];
  const float* W     = (const float*)d_in[2];
  const float* gamma = (const float*)d_in[3];
  const float* beta  = (const float*)d_in[4];
  float* out = (float*)d_out;
  char* ws = (char*)d_ws;

  u16*  hTp = (u16*)(ws);                 //  8,388,608  (Bd*Dd*Nn*2)
  u16*  Wt2 = (u16*)(ws + 8388608);       //  2,621,440  (Dd*KK*2)
  u16*  msg = (u16*)(ws + 11010048);      // 41,943,040  (Bd*Nn*KK*2)
  float* agg = (float*)(ws + 52953088);   // 16,777,216  (Bd*Nn*Dd*4)

  k_prep<<<dim3(5376), dim3(256), 0, stream>>>(h, W, hTp, Wt2, msg);
  k_msg <<<dim3(Bd*32), dim3(512), 0, stream>>>(adj, hTp, msg);
  k_agg <<<dim3(Bd*(Nn/64)*(Dd/128)), dim3(512), 0, stream>>>(msg, Wt2, agg);
  k_ln  <<<dim3(Bd*Nn/4), dim3(256), 0, stream>>>(agg, h, gamma, beta, out);
}

// Round 9
// 92.120 us; speedup vs baseline: 1.1697x; 1.0424x over previous
//
#include <hip/hip_runtime.h>
#include <stdint.h>

#define Bd 8
#define Rr 5
#define Nn 1024
#define Dd 512
#define KK (Rr*Dd) /* 2560 */

typedef __attribute__((ext_vector_type(8))) short bf16x8;
typedef __attribute__((ext_vector_type(4))) float f32x4;
typedef unsigned short u16;
typedef unsigned int u32;

__device__ __forceinline__ u16 f2bf(float x){
  union { float f; unsigned u; } v; v.f = x;
  unsigned r = v.u + 0x7FFFu + ((v.u >> 16) & 1u);
  return (u16)(r >> 16);
}

__device__ __forceinline__ void gll16(const void* g, void* l){
  __builtin_amdgcn_global_load_lds(
      (const __attribute__((address_space(1))) void*)g,
      (__attribute__((address_space(3))) void*)l, 16, 0, 0);
}

// ---------------- K1: fused prep ----------------
__global__ __launch_bounds__(256) void k_prep(
    const float* __restrict__ h, const float* __restrict__ W,
    u16* __restrict__ hTp, u16* __restrict__ Wt2, u16* __restrict__ msg){
  __shared__ float t32[32][65];
  const int tid = threadIdx.x;
  const int g = blockIdx.x;
  if (g < 2048){
    const int ut  = g & 31;
    const int dtg = (g >> 5) & 7;
    const int b   = g >> 8;
    const float* hb = h + ((size_t)b*Nn + (size_t)ut*32)*Dd + dtg*64;
    #pragma unroll
    for (int j=0;j<8;j++){
      int e = j*256 + tid;
      int ul = e >> 6, dl = e & 63;
      t32[ul][dl] = hb[(size_t)ul*Dd + dl];
    }
    __syncthreads();
    u16* ob = hTp + (size_t)b*Dd*Nn;
    #pragma unroll
    for (int j=0;j<8;j++){
      int e = j*256 + tid;
      int dtl = e >> 9;
      int rem = e & 511;
      int dr = rem >> 5, uu = rem & 31;
      int dt = dtg*4 + dtl;
      ob[((size_t)ut*32 + dt)*512 + rem] = f2bf(t32[uu][dtl*16 + dr]);
    }
  } else if (g < 3328){
    int idx = (g - 2048)*1024 + tid*4;     // over 512*2560
    int e = idx / KK;
    int k = idx % KK;
    int ri = (k < 2048) ? (1 + (k >> 9)) : 0;
    int d = k & 511;
    f32x4 w = *(const f32x4*)(W + (((size_t)ri*Dd + e)*Dd + d));
    u16 o[4] = { f2bf(w.x), f2bf(w.y), f2bf(w.z), f2bf(w.w) };
    *(uint2*)(Wt2 + idx) = *(uint2*)o;
  } else {
    int q = g - 3328;                      // 0..2047
    int row = q*4 + (tid >> 6);
    int d0 = (tid & 63)*8;
    f32x4 a = *(const f32x4*)(h + (size_t)row*Dd + d0);
    f32x4 c = *(const f32x4*)(h + (size_t)row*Dd + d0 + 4);
    bf16x8 pk;
    pk[0]=(short)f2bf(a.x); pk[1]=(short)f2bf(a.y);
    pk[2]=(short)f2bf(a.z); pk[3]=(short)f2bf(a.w);
    pk[4]=(short)f2bf(c.x); pk[5]=(short)f2bf(c.y);
    pk[6]=(short)f2bf(c.z); pk[7]=(short)f2bf(c.w);
    *(bf16x8*)(msg + (size_t)row*KK + 2048 + d0) = pk;
  }
}

// ---------------- K2: r-fused msg, cross-barrier B prefetch ----------------
// msg[b][v][(r-1)*512+d] = (1/deg) * sum_u adj[b,r,v,u] h[b,u,d]
// BM=32, BN=512, BK=64, 16 steps, grid 256 (1 block/CU), 512 thr = 8 waves.
// Step body: PACK adj(t+1) [vmcnt leaves B in flight] | AISSUE adj(t+2) |
// MSTEP(t) [bfr loaded LAST step -> no exposed B wait] | LOADB(t+1) |
// lgkm-only raw barrier. No wait ever drains the adj HBM stream (T4).
__global__ __launch_bounds__(512,2) void k_msg(
    const float* __restrict__ adj, const u16* __restrict__ hTp,
    u16* __restrict__ msg){
  __shared__ __align__(16) u16 sA[2][4][32*64];   // 32KB double-buffered adj
  __shared__ float sT[16*516];                    // 33KB epilogue transpose
  __shared__ float sDeg[4][32];

  const int tid  = threadIdx.x;
  const int lane = tid & 63;
  const int wave = tid >> 6;
  const int b  = blockIdx.x & 7;     // b -> XCD (L2 locality for hTp[b])
  const int vt = blockIdx.x >> 3;
  const int v0 = vt * 32;
  const int t0 = blockIdx.x & 15;    // stagger (harmless, breaks alignment)
  const float* adjb = adj + (((size_t)b*Rr + 1)*Nn + v0)*Nn;  // r=1 base
  const u16* hTpb = hTp + (size_t)b*Dd*Nn;

  const int srow = tid >> 4;         // 0..31
  const int sc   = tid & 15;         // 16B chunk
  const size_t aoff = (size_t)srow*Nn + sc*4;
  const int wslot = sc ^ ((srow & 7) << 1);

  float deg[4] = {0.f,0.f,0.f,0.f};
  f32x4 areg[4];
  f32x4 acc[4][2][4];
  #pragma unroll
  for (int ri=0;ri<4;ri++)
    #pragma unroll
    for (int m=0;m<2;m++)
      #pragma unroll
      for (int n=0;n<4;n++) acc[ri][m][n] = (f32x4){0.f,0.f,0.f,0.f};

  const int rlo = lane & 15, ch = lane >> 4;
  const int boff = rlo*32 + ch*8;

  #define TT(x) (((x) + t0) & 15)

  #define AISSUE(T) do {                                                      \
    _Pragma("unroll")                                                         \
    for (int ri=0;ri<4;ri++)                                                  \
      areg[ri] = *(const f32x4*)(adjb + (size_t)ri*Nn*Nn + (size_t)(T)*64 + aoff); \
  } while(0)

  #define PACK(BUFI) do {                                                     \
    _Pragma("unroll")                                                         \
    for (int ri=0;ri<4;ri++){                                                 \
      f32x4 p = areg[ri];                                                     \
      deg[ri] += p.x+p.y+p.z+p.w;                                             \
      uint2 pk;  /* adj in {0,1}: truncation exact */                         \
      pk.x = (__float_as_uint(p.x)>>16) | (__float_as_uint(p.y) & 0xFFFF0000u);\
      pk.y = (__float_as_uint(p.z)>>16) | (__float_as_uint(p.w) & 0xFFFF0000u);\
      *(uint2*)((char*)sA[BUFI][ri] + srow*128 + wslot*8) = pk;               \
    }                                                                         \
  } while(0)

  #define LOADB(T) do {                                                      \
    _Pragma("unroll")                                                         \
    for (int kk=0;kk<2;kk++){                                                 \
      const u16* bp = hTpb + ((((size_t)((T)*2+kk))*32 + (wave<<2))<<9) + boff;\
      _Pragma("unroll")                                                       \
      for (int n=0;n<4;n++)                                                   \
        bfr[kk][n] = *(const bf16x8*)(bp + ((size_t)n<<9));                   \
    }                                                                         \
  } while(0)

  #define MSTEP(BUFI) do {                                                    \
    const char* abase = (const char*)sA[BUFI];                                \
    _Pragma("unroll")                                                         \
    for (int kk=0;kk<2;kk++){                                                 \
      _Pragma("unroll")                                                       \
      for (int ri=0;ri<4;ri++){                                               \
        bf16x8 af[2];                                                         \
        _Pragma("unroll")                                                     \
        for (int m=0;m<2;m++){                                                \
          const int row = m*16 + rlo;                                         \
          af[m] = *(const bf16x8*)(abase + ri*4096 + row*128                  \
                    + (((kk*8 + ch*2) ^ ((row&7)<<1))<<3));                   \
        }                                                                     \
        _Pragma("unroll")                                                     \
        for (int m=0;m<2;m++)                                                 \
          _Pragma("unroll")                                                   \
          for (int n=0;n<4;n++)                                               \
            acc[ri][m][n] = __builtin_amdgcn_mfma_f32_16x16x32_bf16(          \
                af[m], bfr[kk][n], acc[ri][m][n], 0, 0, 0);                   \
      }                                                                       \
    }                                                                         \
  } while(0)

  #define FENCE() __builtin_amdgcn_sched_barrier(0)
  #define STEP_BARRIER() do {                                                 \
    asm volatile("s_waitcnt lgkmcnt(0)" ::: "memory");                        \
    FENCE();                                                                  \
    __builtin_amdgcn_s_barrier();                                             \
    FENCE();                                                                  \
  } while(0)

  bf16x8 bfr[2][4];

  // prologue: pack tile TT(0) -> buf0; B(TT(0)) oldest in FIFO; adj(TT(1)) next
  AISSUE(TT(0));
  PACK(0);
  __syncthreads();
  LOADB(TT(0));
  FENCE();
  AISSUE(TT(1));
  FENCE();

  for (int t = 0; t < 15; ++t){
    PACK((t+1)&1);             // consumes adj(t+1); vmcnt wait leaves B in flight
    FENCE();
    if (t < 14) AISSUE(TT(t+2));  // adj(t+2): ~1 full step in flight
    FENCE();
    MSTEP(t&1);                // bfr loaded last step: no exposed B wait
    FENCE();
    LOADB(TT(t+1));            // B(t+1) crosses the barrier in registers
    STEP_BARRIER();
  }
  MSTEP(1);                    // t = 15
  #undef TT
  #undef AISSUE
  #undef PACK
  #undef LOADB
  #undef MSTEP
  #undef FENCE
  #undef STEP_BARRIER

  // deg reduce over the 16 threads sharing srow
  #pragma unroll
  for (int ri=0;ri<4;ri++){
    float d = deg[ri];
    d += __shfl_xor(d, 1); d += __shfl_xor(d, 2);
    d += __shfl_xor(d, 4); d += __shfl_xor(d, 8);
    if (sc == 0) sDeg[ri][srow] = d;
  }
  __syncthreads();

  // Epilogue: per (ri, half): scale -> swizzled sT -> dense 1KB-row stores
  u16* mb = msg + ((size_t)b*Nn + v0)*KK;
  #pragma unroll
  for (int ri=0;ri<4;ri++){
    #pragma unroll
    for (int hh=0;hh<2;hh++){
      #pragma unroll
      for (int reg=0;reg<4;reg++){
        const int rl = ch*4 + reg;
        const float inv = 1.0f / fmaxf(sDeg[ri][hh*16 + rl], 1.0f);
        #pragma unroll
        for (int n=0;n<4;n++){
          const int col = (wave<<6) + n*16 + rlo;
          const int colw = col ^ (((col>>5)&7)<<2);
          sT[rl*516 + colw] = acc[ri][hh][n][reg] * inv;
        }
      }
      __syncthreads();
      #pragma unroll
      for (int s=0;s<2;s++){
        const int rl = wave*2 + s;
        const int m5 = lane >> 2;
        const int e  = m5 & 7;
        const int j0 = (2*lane) & 7;
        f32x4 lo = *(const f32x4*)&sT[rl*516 + (m5<<5) + (((j0  ) ^ e)<<2)];
        f32x4 hi = *(const f32x4*)&sT[rl*516 + (m5<<5) + (((j0+1) ^ e)<<2)];
        bf16x8 pk;
        pk[0]=(short)f2bf(lo.x); pk[1]=(short)f2bf(lo.y);
        pk[2]=(short)f2bf(lo.z); pk[3]=(short)f2bf(lo.w);
        pk[4]=(short)f2bf(hi.x); pk[5]=(short)f2bf(hi.y);
        pk[6]=(short)f2bf(hi.z); pk[7]=(short)f2bf(hi.w);
        *(bf16x8*)(mb + (size_t)(hh*16 + rl)*KK + ri*512 + lane*8) = pk;
      }
      __syncthreads();
    }
  }
}

// ---------------- K3: agg[b][v][e] = sum_k msg[b][v][k] * Wt2[e][k], K=2560
__global__ __launch_bounds__(512,4) void k_agg(
    const u16* __restrict__ msg, const u16* __restrict__ Wt,
    float* __restrict__ agg){
  __shared__ __align__(16) u16 sA[2][64*64];
  __shared__ __align__(16) u16 sB[2][128*64];
  const int tid = threadIdx.x;
  const int lane = tid & 63, wave = tid >> 6;
  const int wm = wave >> 2, wn = wave & 3;
  const int g = blockIdx.x;
  const int et = g >> 7;
  const int bv = g & 127;
  const int b  = bv >> 4;
  const int vt = bv & 15;
  const int v0 = vt*64, e0 = et*128;
  const u16* Ab = msg + ((size_t)b*Nn + v0)*KK;
  const u16* Bb = Wt + (size_t)e0*KK;

  f32x4 acc[2][2];
  #pragma unroll
  for (int m=0;m<2;m++)
    #pragma unroll
    for (int n=0;n<2;n++) acc[m][n] = (f32x4){0.f,0.f,0.f,0.f};

  #define STAGE(buf, kt) do {                                              \
    { int c = tid; int row_ = c>>3, chg = (c&7) ^ (row_&7);                \
      gll16(Ab + (size_t)row_*KK + (kt)*64 + chg*8,                        \
            (char*)sA[buf] + ((size_t)(wave<<6))*16); }                    \
    _Pragma("unroll")                                                      \
    for (int i=0;i<2;i++){                                                 \
      int c = i*512 + tid; int row_ = c>>3, chg = (c&7) ^ (row_&7);        \
      gll16(Bb + (size_t)row_*KK + (kt)*64 + chg*8,                        \
            (char*)sB[buf] + ((size_t)(i*512 + (wave<<6)))*16);            \
    }                                                                      \
  } while(0)

  STAGE(0, 0);
  __syncthreads();

  const int ch = lane >> 4, rlo = lane & 15;

  for (int kt = 0; kt < KK/64; ++kt){
    if (kt < KK/64 - 1) STAGE((kt+1)&1, kt+1);
    const char* a  = (const char*)sA[kt&1];
    const char* bb = (const char*)sB[kt&1];
    #pragma unroll
    for (int kk=0; kk<2; ++kk){
      bf16x8 af[2], bfx[2];
      #pragma unroll
      for (int m=0;m<2;m++){
        const int row = wm*32 + m*16 + rlo;
        af[m] = *(const bf16x8*)(a + row*128 + ((((kk<<2)+ch) ^ (row&7))<<4));
      }
      #pragma unroll
      for (int n=0;n<2;n++){
        const int row = wn*32 + n*16 + rlo;
        bfx[n] = *(const bf16x8*)(bb + row*128 + ((((kk<<2)+ch) ^ (row&7))<<4));
      }
      #pragma unroll
      for (int m=0;m<2;m++)
        #pragma unroll
        for (int n=0;n<2;n++)
          acc[m][n] = __builtin_amdgcn_mfma_f32_16x16x32_bf16(af[m], bfx[n], acc[m][n], 0, 0, 0);
    }
    __syncthreads();
  }
  #undef STAGE

  float* ob = agg + ((size_t)b*Nn + v0)*Dd + e0;
  #pragma unroll
  for (int m=0;m<2;m++)
    #pragma unroll
    for (int reg=0;reg<4;reg++){
      const int row = wm*32 + m*16 + ((lane>>4)<<2) + reg;
      #pragma unroll
      for (int n=0;n<2;n++){
        const int col = wn*32 + n*16 + (lane & 15);
        ob[(size_t)row*Dd + col] = acc[m][n][reg];
      }
    }
}

// ---------------- K4: out = LN(relu(agg) + h) * gamma + beta; 4 rows/block
__global__ __launch_bounds__(256,4) void k_ln(
    const float* __restrict__ agg, const float* __restrict__ h,
    const float* __restrict__ gamma, const float* __restrict__ beta,
    float* __restrict__ out){
  const int row = blockIdx.x*4 + (threadIdx.x >> 6);
  const int lane = threadIdx.x & 63;
  const float* a  = agg + (size_t)row*Dd;
  const float* hh = h   + (size_t)row*Dd;
  float x[8];
  float sum = 0.f, sq = 0.f;
  #pragma unroll
  for (int q=0;q<2;q++){
    f32x4 av = *(const f32x4*)(a  + ((size_t)q*64+lane)*4);
    f32x4 hv = *(const f32x4*)(hh + ((size_t)q*64+lane)*4);
    #pragma unroll
    for (int k=0;k<4;k++){
      float v = fmaxf(av[k], 0.f) + hv[k];
      x[q*4+k] = v; sum += v; sq += v*v;
    }
  }
  #pragma unroll
  for (int off=32; off; off>>=1){
    sum += __shfl_xor(sum, off);
    sq  += __shfl_xor(sq,  off);
  }
  const float mu  = sum * (1.f/(float)Dd);
  const float var = sq * (1.f/(float)Dd) - mu*mu;
  const float rstd = rsqrtf(var + 1e-5f);
  float* o = out + (size_t)row*Dd;
  #pragma unroll
  for (int q=0;q<2;q++){
    f32x4 g  = *(const f32x4*)(gamma + ((size_t)q*64+lane)*4);
    f32x4 be = *(const f32x4*)(beta  + ((size_t)q*64+lane)*4);
    f32x4 ov;
    #pragma unroll
    for (int k=0;k<4;k++)
      ov[k] = (x[q*4+k] - mu) * rstd * g[k] + be[k];
    *(f32x4*)(o + ((size_t)q*64+lane)*4) = ov;
  }
}

extern "C" void kernel_launch(void* const* d_in, const int* in_sizes, int n_in,
                              void* d_out, int out_size, void* d_ws, size_t ws_size,
                              hipStream_t stream){
  const float* h     = (const float*)d_in[0];
  const float* adj   = (const float*)d_in[1];
  const float* W     = (const float*)d_in[2];
  const float* gamma = (const float*)d_in[3];
  const float* beta  = (const float*)d_in[4];
  float* out = (float*)d_out;
  char* ws = (char*)d_ws;

  u16*  hTp = (u16*)(ws);                 //  8,388,608  (Bd*Dd*Nn*2)
  u16*  Wt2 = (u16*)(ws + 8388608);       //  2,621,440  (Dd*KK*2)
  u16*  msg = (u16*)(ws + 11010048);      // 41,943,040  (Bd*Nn*KK*2)
  float* agg = (float*)(ws + 52953088);   // 16,777,216  (Bd*Nn*Dd*4)

  k_prep<<<dim3(5376), dim3(256), 0, stream>>>(h, W, hTp, Wt2, msg);
  k_msg <<<dim3(Bd*32), dim3(512), 0, stream>>>(adj, hTp, msg);
  k_agg <<<dim3(Bd*(Nn/64)*(Dd/128)), dim3(512), 0, stream>>>(msg, Wt2, agg);
  k_ln  <<<dim3(Bd*Nn/4), dim3(256), 0, stream>>>(agg, h, gamma, beta, out);
}